// Round 8
// baseline (107.826 us; speedup 1.0000x reference)
//
#include <hip/hip_runtime.h>

constexpr int N_NODES = 100000;
constexpr int N_FEAT  = 512;
constexpr int N_EDGES = 1600000;

// fixed-point packing for LDS u64 accumulation
constexpr float FXS = 1048576.0f;  // 2^20
constexpr float FXB = 32.0f;       // positivity bias; FXB*FXS = 2^25 exact

// binning
constexpr int BSH   = 8;
constexpr int BINW  = 1 << BSH;                     // 256 nodes/bin
constexpr int NBINS = (N_NODES + BINW - 1) >> BSH;  // 391
constexpr int BCAP  = 5120;  // bin degree-sum: mean 4092, +16 sigma
constexpr int GRID  = 2048;  // every block bins AND row-dots (round-7 lesson:
                             // any block-role split idles CUs)
constexpr int CHUNK = (N_EDGES + GRID - 1) / GRID;  // 782

typedef float vfloat4 __attribute__((ext_vector_type(4)));

// ws float offsets
constexpr int WS_W    = 0;                    // [0,1024) two cols of w1@w2
constexpr int WS_C    = 1024;                 // c (pad to 1056)
constexpr int WS_CUR  = 1056;                 // NBINS cursors (pad 512)
constexpr int WS_DEG  = WS_CUR + 512;         // deg[N] int
constexpr int WS_DINV = WS_DEG + N_NODES;     // dinv[N]
constexpr int WS_G    = WS_DINV + N_NODES;    // g[N,2] (byte%8==0)
constexpr int WS_FXP  = WS_G + 2 * N_NODES;   // u64[N] packed addends
constexpr int WS_BINS = WS_FXP + 2 * N_NODES; // u32[NBINS*BCAP] ~8MB

static_assert((WS_FXP * 4) % 8 == 0, "fxp alignment");
static_assert(N_NODES % 4 == 0, "");

// ---- kernel 1: W = w1@w2, c = b1@w2+b2, zero cursors ----
__global__ void k_prep(const float* __restrict__ w1, const float* __restrict__ w2,
                       const float* __restrict__ b1, const float* __restrict__ b2,
                       float* __restrict__ ws) {
    int i = blockIdx.x * blockDim.x + threadIdx.x;
    if (i < NBINS) reinterpret_cast<int*>(ws + WS_CUR)[i] = 0;
    if (i < N_FEAT) {
        float a0 = 0.f, a1 = 0.f;
        for (int m = 0; m < 128; ++m) {
            float w = w1[i * 128 + m];
            a0 += w * w2[m * 2 + 0];
            a1 += w * w2[m * 2 + 1];
        }
        ws[WS_W + i] = a0;
        ws[WS_W + 512 + i] = a1;
        if (i < 2) {
            float s = b2[i];
            for (int m = 0; m < 128; ++m) s += b1[m] * w2[m * 2 + i];
            ws[WS_C + i] = s;
        }
    }
}

// ---- kernel 2: EVERY block: phase A = bin 782 edges; phase B = rowdot ----
__global__ __launch_bounds__(256) void k_fused(
    const float* __restrict__ x, float* __restrict__ ws,
    const int* __restrict__ src, const int* __restrict__ dst,
    float2* __restrict__ g) {
    int b = blockIdx.x;
    int tid = threadIdx.x;

    // ---- phase A: binning (count -> reserve -> place), ~782 edges/block ----
    {
        __shared__ int cnt[NBINS];
        __shared__ int offs[NBINS];
        __shared__ int cur2[NBINS];
        for (int i = tid; i < NBINS; i += 256) { cnt[i] = 0; cur2[i] = 0; }
        __syncthreads();
        int base = b * CHUNK;
        int end  = min(base + CHUNK, N_EDGES);
        for (int e = base + tid; e < end; e += 256)
            atomicAdd(&cnt[dst[e] >> BSH], 1);
        __syncthreads();
        int* gcur = reinterpret_cast<int*>(ws + WS_CUR);
        for (int i = tid; i < NBINS; i += 256) {
            int c = cnt[i];
            int pos = c ? atomicAdd(&gcur[i], c) : 0;
            offs[i] = i * BCAP + pos;
        }
        __syncthreads();
        unsigned int* bins = reinterpret_cast<unsigned int*>(ws + WS_BINS);
        for (int e = base + tid; e < end; e += 256) {
            int d = dst[e], s = src[e];
            int bin = d >> BSH;
            int r = atomicAdd(&cur2[bin], 1);
            bins[offs[bin] + r] = (unsigned int)s | ((unsigned int)(d & (BINW - 1)) << 17);
        }
        // LDS not reused below; no extra sync needed
    }

    // ---- phase B: rowdot, 4 rows per wave-iteration, 16 lanes per row ----
    const vfloat4* W0q = reinterpret_cast<const vfloat4*>(ws + WS_W);
    const vfloat4* W1q = reinterpret_cast<const vfloat4*>(ws + WS_W + 512);
    int lane = tid & 63;
    int wave = tid >> 6;
    int j = lane & 15, i4 = lane >> 4;

    vfloat4 w0[8], w1[8];
    #pragma unroll
    for (int k = 0; k < 8; ++k) {
        w0[k] = W0q[k * 16 + j];
        w1[k] = W1q[k * 16 + j];
    }

    int wid = b * 4 + wave;
    int nw  = GRID * 4;                   // 8192
    constexpr int NQ = N_NODES / 4;       // 25000
    for (int q = wid; q < NQ; q += nw) {
        int row = q * 4 + i4;
        const vfloat4* xr = reinterpret_cast<const vfloat4*>(x + (size_t)row * N_FEAT);
        vfloat4 xv[8];
        #pragma unroll
        for (int k = 0; k < 8; ++k)
            xv[k] = __builtin_nontemporal_load(&xr[k * 16 + j]);
        float a0 = 0.f, a1 = 0.f;
        #pragma unroll
        for (int k = 0; k < 8; ++k) {
            a0 += xv[k].x*w0[k].x + xv[k].y*w0[k].y + xv[k].z*w0[k].z + xv[k].w*w0[k].w;
            a1 += xv[k].x*w1[k].x + xv[k].y*w1[k].y + xv[k].z*w1[k].z + xv[k].w*w1[k].w;
        }
        #pragma unroll
        for (int off = 1; off <= 8; off <<= 1) {
            a0 += __shfl_xor(a0, off);
            a1 += __shfl_xor(a1, off);
        }
        if (j == 0) g[row] = make_float2(a0, a1);
    }
}

// ---- kernel 3: per-bin degree count; write deg, dinv, packed addend fxp ----
__global__ __launch_bounds__(256) void k_deg(float* __restrict__ ws) {
    int b = blockIdx.x;
    const int* gcur = reinterpret_cast<const int*>(ws + WS_CUR);
    const unsigned int* bins = reinterpret_cast<const unsigned int*>(ws + WS_BINS) + b * BCAP;
    int n = min(gcur[b], BCAP);
    __shared__ int cnt[BINW];
    cnt[threadIdx.x] = 0;
    __syncthreads();
    for (int i = threadIdx.x; i < n; i += 256)
        atomicAdd(&cnt[bins[i] >> 17], 1);
    __syncthreads();
    int d = (b << BSH) + threadIdx.x;
    if (d < N_NODES) {
        int dg = cnt[threadIdx.x] + 1;               // + self-loop
        reinterpret_cast<int*>(ws + WS_DEG)[d] = dg;
        float di = rsqrtf((float)dg);
        ws[WS_DINV + d] = di;
        float2 gv = reinterpret_cast<const float2*>(ws + WS_G)[d];
        unsigned int lo = (unsigned int)__float2int_rn((gv.x * di + FXB) * FXS);
        unsigned int hi = (unsigned int)__float2int_rn((gv.y * di + FXB) * FXS);
        reinterpret_cast<unsigned long long*>(ws + WS_FXP)[d] =
            ((unsigned long long)hi << 32) | (unsigned long long)lo;
    }
}

// ---- kernel 4: per-bin LDS u64 accumulation of fxp[src]; finalize ----
__global__ __launch_bounds__(256) void k_pass2(float* __restrict__ ws,
                                               float2* __restrict__ out) {
    int b = blockIdx.x;
    const int* gcur = reinterpret_cast<const int*>(ws + WS_CUR);
    const unsigned int* bins = reinterpret_cast<const unsigned int*>(ws + WS_BINS) + b * BCAP;
    const int* deg = reinterpret_cast<const int*>(ws + WS_DEG);
    const float* dinv = ws + WS_DINV;
    const unsigned long long* fxp = reinterpret_cast<const unsigned long long*>(ws + WS_FXP);
    int n = min(gcur[b], BCAP);
    __shared__ unsigned long long acc[BINW];
    acc[threadIdx.x] = 0ull;
    __syncthreads();
    for (int i = threadIdx.x; i < n; i += 256) {
        unsigned int p = bins[i];
        atomicAdd(&acc[p >> 17], fxp[p & 0x1FFFFu]);
    }
    __syncthreads();
    int d = (b << BSH) + threadIdx.x;
    if (d < N_NODES) {
        unsigned long long a = acc[threadIdx.x] + fxp[d];   // + self-loop addend
        long long dg = (long long)deg[d];
        long long bias = dg << 25;                           // exact: deg * FXB*FXS
        long long lo = (long long)(a & 0xFFFFFFFFull) - bias;
        long long hi = (long long)(a >> 32) - bias;
        float di = dinv[d];
        out[d] = make_float2(di * ((float)lo * (1.0f / FXS)) + ws[WS_C + 0],
                             di * ((float)hi * (1.0f / FXS)) + ws[WS_C + 1]);
    }
}

extern "C" void kernel_launch(void* const* d_in, const int* in_sizes, int n_in,
                              void* d_out, int out_size, void* d_ws, size_t ws_size,
                              hipStream_t stream) {
    const float* x  = (const float*)d_in[0];
    const float* w1 = (const float*)d_in[1];
    const float* b1 = (const float*)d_in[2];
    const float* w2 = (const float*)d_in[3];
    const float* b2 = (const float*)d_in[4];
    const int*   ei = (const int*)d_in[5];   // [2, E]: src row then dst row
    float* ws = (float*)d_ws;

    float2* g = (float2*)(ws + WS_G);

    k_prep<<<2, 256, 0, stream>>>(w1, w2, b1, b2, ws);
    k_fused<<<GRID, 256, 0, stream>>>(x, ws, ei, ei + N_EDGES, g);
    k_deg<<<NBINS, 256, 0, stream>>>(ws);
    k_pass2<<<NBINS, 256, 0, stream>>>(ws, (float2*)d_out);
}